// Round 6
// baseline (554.466 us; speedup 1.0000x reference)
//
#include <hip/hip_runtime.h>

#define E_DIM  256
#define N_E    16384
#define N_ROWS 8192
#define HW     1024
#define NPART  64           // n-tiles of 256 cols

typedef _Float16 f16x8 __attribute__((ext_vector_type(8)));
typedef float    f32x4 __attribute__((ext_vector_type(4)));

#define ESCALE   1048576.0f          // 2^20 (exact)
#define UNSCALE  1.9073486328125e-6f // 2^-19: acc*2^-19 == 2*dot (approx, single limb)

// async 16B global->LDS copy: HW writes lds_base + lane*16 (wave-uniform base)
__device__ __forceinline__ void gld_lds16(_Float16* lds, const _Float16* g) {
  __builtin_amdgcn_global_load_lds(
      (__attribute__((address_space(1))) void*)(g),
      (__attribute__((address_space(3))) void*)(lds), 16, 0, 0);
}

// reference-semantics f32 score: fl32(fl32(zn+en) - fl32(2*dot_f64)).
// f64 dot is correctly rounded; final f32 rounding at ulp(~256) reproduces
// numpy's d bucket; equal buckets resolve by lex idx (caller).
__device__ __forceinline__ float score_ref(const float* zr,
                                           const float* __restrict__ E,
                                           const float* __restrict__ eNorm,
                                           int idx, float zn) {
  const float4* e4p = (const float4*)(E + (size_t)idx * E_DIM);
  double dot = 0.0;
#pragma unroll 8
  for (int q = 0; q < 64; ++q) {
    float4 e4 = e4p[q];
    dot = fma((double)zr[q * 4 + 0], (double)e4.x, dot);
    dot = fma((double)zr[q * 4 + 1], (double)e4.y, dot);
    dot = fma((double)zr[q * 4 + 2], (double)e4.z, dot);
    dot = fma((double)zr[q * 4 + 3], (double)e4.w, dot);
  }
  float base = zn + eNorm[idx];   // f32 add, matches np broadcast add
  float td = (float)(2.0 * dot);  // correctly-rounded 2*dot
  return base - td;               // f32 final rounding at the reference ulp
}

// ---------- fused prep: single-limb A/B + eNorm + numpy-exact zNorm + z L1 ----------
#define ZB_Z    256
#define EB_E    512
__global__ __launch_bounds__(256) void k_prep(const float* __restrict__ z,
                                              const float* __restrict__ E,
                                              _Float16* __restrict__ Ah,
                                              _Float16* __restrict__ Bh,
                                              float* __restrict__ eNorm,
                                              float* __restrict__ zNorm,
                                              float* __restrict__ zL1,
                                              float* __restrict__ out_loss) {
#pragma clang fp contract(off)
  const int bi = blockIdx.x, t = threadIdx.x;

  if (bi < ZB_Z) {
    // ---- z section: 32-row tile ----
    __shared__ float sLZ[256][32];   // 32 KB z tile [channel][row]
    __shared__ float sN2[16][32];    // square-chain partials [c16][row]
    __shared__ float sL1[16][32];    // abs-chain partials
    const int n0 = bi * 32;
    const int b = n0 >> 10, hw0 = n0 & 1023;

    {
      const int nl = t & 31, cs = t >> 5;
      const float* zb = z + (size_t)b * E_DIM * HW + hw0 + nl;
#pragma unroll 4
      for (int it = 0; it < 32; ++it) {
        int c = it * 8 + cs;
        sLZ[c][nl] = zb[(size_t)c * HW];
      }
    }
    __syncthreads();

    // phase L: high limb only. thread = (row nl, segment seg = kc)
    {
      const int nl = t & 31, seg = t >> 5;
      const int n = n0 + nl;
      const int perm = (n >> 1) & 3;
#pragma unroll
      for (int u = 0; u < 4; ++u) {
        const int c0 = seg * 32 + u * 8;
        f16x8 hh;
#pragma unroll
        for (int j = 0; j < 8; ++j) hh[j] = (_Float16)sLZ[c0 + j][nl];
        size_t dst = (size_t)seg * (N_ROWS * 32) + (size_t)n * 32 + (size_t)(u ^ perm) * 8;
        *(f16x8*)&Ah[dst] = hh;
      }
    }

    // phase N: numpy-exact square chains (zNorm) + abs chains (zL1 window scale)
#pragma unroll
    for (int it = 0; it < 2; ++it) {
      int task = it * 256 + t;
      int nl = task & 31, c16 = task >> 5;
      int h = c16 >> 3, j = c16 & 7;
      float r2 = 0.f, r1 = 0.f;
#pragma unroll
      for (int i = 0; i < 16; ++i) {
        float v = sLZ[h * 128 + i * 8 + j][nl];
        r2 = r2 + v * v;
        r1 = r1 + fabsf(v);
      }
      sN2[c16][nl] = r2;
      sL1[c16][nl] = r1;
    }
    __syncthreads();
    if (t < 32) {
      float q[16], p[16];
#pragma unroll
      for (int c16 = 0; c16 < 16; ++c16) { q[c16] = sN2[c16][t]; p[c16] = sL1[c16][t]; }
      float h0 = ((q[0] + q[1]) + (q[2] + q[3])) + ((q[4] + q[5]) + (q[6] + q[7]));
      float h1 = ((q[8] + q[9]) + (q[10] + q[11])) + ((q[12] + q[13]) + (q[14] + q[15]));
      zNorm[n0 + t] = h0 + h1;
      float g0 = ((p[0] + p[1]) + (p[2] + p[3])) + ((p[4] + p[5]) + (p[6] + p[7]));
      float g1 = ((p[8] + p[9]) + (p[10] + p[11])) + ((p[12] + p[13]) + (p[14] + p[15]));
      zL1[n0 + t] = g0 + g1;
    }
  } else {
    // ---- E section ----
    __shared__ float sNP[8][32];
    const int be = bi - ZB_Z;
    if (be == 0 && t == 0) out_loss[0] = 0.f;
    const int kc = t >> 5, rl = t & 31;
    const int k = be * 32 + rl;
    const int perm = (k >> 1) & 3;
    const float* src = E + (size_t)k * E_DIM + kc * 32;

    float4 v4[8];
#pragma unroll
    for (int u2 = 0; u2 < 8; ++u2) v4[u2] = ((const float4*)src)[u2];

    float nsum = 0.f;
    size_t base = (size_t)kc * (N_E * 32) + (size_t)k * 32;
#pragma unroll
    for (int u = 0; u < 4; ++u) {
      float v[8] = {v4[u * 2].x, v4[u * 2].y, v4[u * 2].z, v4[u * 2].w,
                    v4[u * 2 + 1].x, v4[u * 2 + 1].y, v4[u * 2 + 1].z, v4[u * 2 + 1].w};
      f16x8 hh;
#pragma unroll
      for (int j = 0; j < 8; ++j) {
        nsum = nsum + v[j] * v[j];
        hh[j] = (_Float16)(v[j] * ESCALE);
      }
      *(f16x8*)&Bh[base + (size_t)(u ^ perm) * 8] = hh;
    }
    sNP[kc][rl] = nsum;
    __syncthreads();
    if (t < 32) {
      float s = 0.f;
#pragma unroll
      for (int kc2 = 0; kc2 < 8; ++kc2) s += sNP[kc2][t];
      eNorm[be * 32 + t] = s;
    }
  }
}

// ---------- main: single-limb approx GEMM + R18 branchless packed-key top-2.
// key = quantize18(s) << 14 | idx  (s in (-1/16,1/16) guaranteed by
// |2 z.e| <= 2||z|| ||e|| < 0.04); u32 min == lex (s, idx) min.
// Quantizer folded into one fmaf: UNSCALE*2^21 == 4.0 exactly.
__global__ __launch_bounds__(512, 2) void k_scores_mfma(
    const _Float16* __restrict__ Ah, const _Float16* __restrict__ Bh,
    const float* __restrict__ eNorm,
    unsigned* __restrict__ pK1, unsigned* __restrict__ pK2) {
#pragma clang fp contract(off)
  __shared__ alignas(16) _Float16 As[2][256][32];  // 32 KB (dbuf)
  __shared__ alignas(16) _Float16 Bs[2][256][32];  // 32 KB

  const int mt = blockIdx.x, nt = blockIdx.y;
  const int m0 = mt * 256, n0 = nt * 256;

  const int t = threadIdx.x;
  const int lane = t & 63, w = t >> 6;
  const int tx = lane & 15, quad = lane >> 4;
  const int wr = w & 3, wc = w >> 2;          // wave grid 4 (m) x 2 (n)
  const int wm = wr * 64, wn = wc * 128;      // per-wave output 64 x 128
  const int swz = (quad ^ ((tx >> 1) & 3)) * 8;  // physical f16 offset of logical block

  // staging role: waves 0-3 stage A rows [w*64,w*64+64), waves 4-7 stage B
  const _Float16* gstage;
  size_t plane;
  _Float16* ls0;
  if (w < 4) { gstage = Ah + (size_t)(m0 + w * 64) * 32;       plane = (size_t)N_ROWS * 32; ls0 = &As[0][w * 64][0]; }
  else       { gstage = Bh + (size_t)(n0 + (w - 4) * 64) * 32; plane = (size_t)N_E * 32;    ls0 = &Bs[0][(w - 4) * 64][0]; }
  gstage += lane * 8;

  f32x4 acc[4][8];
#pragma unroll
  for (int i = 0; i < 4; ++i)
#pragma unroll
    for (int j = 0; j < 8; ++j) acc[i][j] = (f32x4){0.f, 0.f, 0.f, 0.f};

  // prologue: stage kc=0 into buf 0 (4 x 1KB per wave)
#pragma unroll
  for (int c = 0; c < 4; ++c) gld_lds16(ls0 + c * 512, gstage + c * 512);
  __syncthreads();

  for (int kc = 0; kc < 8; ++kc) {
    const int buf = kc & 1;

    if (kc < 7) {
      _Float16* lpre = ls0 + (size_t)(buf ^ 1) * 8192;
      const _Float16* gpre = gstage + (size_t)(kc + 1) * plane;
#pragma unroll
      for (int c = 0; c < 4; ++c) gld_lds16(lpre + c * 512, gpre + c * 512);
      __builtin_amdgcn_sched_barrier(0);   // pin prefetch issue before compute
    }

    f16x8 ah[4], bh[8];
#pragma unroll
    for (int i = 0; i < 4; ++i)
      ah[i] = *(const f16x8*)&As[buf][wm + i * 16 + tx][swz];
#pragma unroll
    for (int j = 0; j < 8; ++j)
      bh[j] = *(const f16x8*)&Bs[buf][wn + j * 16 + tx][swz];

    __builtin_amdgcn_s_setprio(1);
#pragma unroll
    for (int j = 0; j < 8; ++j)
#pragma unroll
      for (int i = 0; i < 4; ++i)
        acc[i][j] = __builtin_amdgcn_mfma_f32_16x16x32_f16(ah[i], bh[j], acc[i][j], 0, 0, 0);
    __builtin_amdgcn_s_setprio(0);

    __syncthreads();   // kc boundary: drains prefetch (1 full kc of cover) + frag reads
  }

  // ---- epilogue: branchless packed-key top-2 per (row, tile) ----
  float* sF  = (float*)&As[0][0][0];
  float* eNq = sF;                          // [256] quantized-domain eNorm
  unsigned* sK1 = (unsigned*)(sF + 256);    // [2][256]
  unsigned* sK2 = sK1 + 512;                // [2][256]
  if (t < 256) eNq[t] = fmaf(eNorm[n0 + t], 2097152.f, 131072.f);
  __syncthreads();

#pragma unroll
  for (int i = 0; i < 4; ++i) {
#pragma unroll
    for (int r = 0; r < 4; ++r) {
      const int rloc = wm + i * 16 + quad * 4 + r;
      unsigned m1 = 0xFFFFFFFFu, m2 = 0xFFFFFFFFu;
#pragma unroll
      for (int jj = 0; jj < 8; ++jj) {
        const int col = wn + jj * 16 + tx;
        float tq = fmaf(acc[i][jj][r], -4.0f, eNq[col]);   // (s - SMIN)*2^21
        unsigned key = (((unsigned)tq) << 14) | (unsigned)(n0 + col);
        m2 = min(m2, max(m1, key));
        m1 = min(m1, key);
      }
#pragma unroll
      for (int off = 1; off < 16; off <<= 1) {
        unsigned om1 = (unsigned)__shfl_xor((int)m1, off, 64);
        unsigned om2 = (unsigned)__shfl_xor((int)m2, off, 64);
        m2 = min(min(m2, om2), max(m1, om1));
        m1 = min(m1, om1);
      }
      if (tx == 0) { sK1[wc * 256 + rloc] = m1; sK2[wc * 256 + rloc] = m2; }
    }
  }
  __syncthreads();
  if (t < 256) {
    unsigned a1 = sK1[t], a2 = sK2[t];
    unsigned b1 = sK1[256 + t], b2 = sK2[256 + t];
    const size_t o = (size_t)nt * N_ROWS + m0 + t;
    pK1[o] = min(a1, b1);
    pK2[o] = min(max(a1, b1), min(a2, b2));
  }
}

// ---------- fused post: key-domain window + REFERENCE-f32 rescore ----------
__global__ __launch_bounds__(256) void k_post(
    const unsigned* __restrict__ pK1, const unsigned* __restrict__ pK2,
    const float* __restrict__ zL1, const float* __restrict__ zNorm,
    const float* __restrict__ z, const float* __restrict__ E,
    const float* __restrict__ eNorm,
    float* __restrict__ out, float* __restrict__ out_loss,
    float* __restrict__ out_idx) {
#pragma clang fp contract(off)
  __shared__ float zc[32][260];     // z rows cache (+pad)
  __shared__ unsigned sM[8][32];
  __shared__ unsigned gK[32];
  __shared__ int   fI[32];
  __shared__ int   cand[32][16];
  __shared__ int   ccnt[32];
  __shared__ int   heavy[32][4];
  __shared__ int   hcnt[32];
  __shared__ float fS[32][8];
  __shared__ int   fiS[32][8];
  __shared__ float wsum[4];

  const int t = threadIdx.x;
  const int r = t & 31, s = t >> 5;
  const int n0 = blockIdx.x * 32;
  const int n = n0 + r;
  const int b = n >> 10, hw = n & 1023;

  if (t < 32) { ccnt[t] = 0; hcnt[t] = 0; }

  // cache this row's z (reused by rescore AND final gather/loss)
  {
    const float* zrow = z + ((size_t)b * E_DIM + s * 32) * HW + hw;
#pragma unroll
    for (int k = 0; k < 32; ++k) zc[r][s * 32 + k] = zrow[(size_t)k * HW];
  }

  // (A) global approx min over 64 tiles (u32 key min == lex (s, idx) min)
  unsigned mk = 0xFFFFFFFFu;
#pragma unroll
  for (int i = 0; i < 8; ++i) {
    int ti = s * 8 + i;
    mk = min(mk, pK1[(size_t)ti * N_ROWS + n]);
  }
  sM[s][r] = mk;
  __syncthreads();
  if (t < 32) {
    unsigned bk = sM[0][t];
#pragma unroll
    for (int s3 = 1; s3 < 8; ++s3) bk = min(bk, sM[s3][t]);
    gK[t] = bk;
  }
  __syncthreads();

  // (B) window in key space: W = 2^-22*||z||_1 + 8e-5, +3 quant steps slack
  {
    const unsigned qW =
        (unsigned)(fmaf(zL1[n], 2.384185791015625e-7f, 8e-5f) * 2097152.f) + 3u;
    unsigned thrq = (gK[r] >> 14) + qW;
    if (thrq > 262143u) thrq = 262143u;
    const unsigned thrk = (thrq << 14) | 0x3FFFu;
#pragma unroll
    for (int i = 0; i < 8; ++i) {
      int ti = s * 8 + i;
      size_t o = (size_t)ti * N_ROWS + n;
      unsigned k1 = pK1[o], k2 = pK2[o];
      if (k1 <= thrk) { int p = atomicAdd(&ccnt[r], 1); if (p < 16) cand[r][p] = (int)(k1 & 0x3FFFu); }
      if (k2 <= thrk) { int p = atomicAdd(&hcnt[r], 1); if (p < 4)  heavy[r][p] = ti; }
    }
  }
  __syncthreads();

  // (C) reference-f32 rescore of window members; lexicographic (s_p, idx) min
  {
    const int rcnt = ccnt[r], rhc = hcnt[r];
    const bool ovf = (rcnt > 16) || (rhc > 4);
    const bool ex = (rcnt > 1) || (rhc > 0);
    float bv = 3.4e38f;
    int bi = 0x7fffffff;
    if (ex) {
      const float zn = zNorm[n];
      if (ovf) {
        for (int k = s; k < N_E; k += 8) {
          float sp = score_ref(&zc[r][0], E, eNorm, k, zn);
          if (sp < bv || (sp == bv && k < bi)) { bv = sp; bi = k; }
        }
      } else {
        for (int c = s; c < rcnt; c += 8) {
          int idx = cand[r][c];
          float sp = score_ref(&zc[r][0], E, eNorm, idx, zn);
          if (sp < bv || (sp == bv && idx < bi)) { bv = sp; bi = idx; }
        }
        for (int h = 0; h < rhc; ++h) {
          int ti = heavy[r][h];
          for (int cc = s; cc < 256; cc += 8) {
            int idx = ti * 256 + cc;
            float sp = score_ref(&zc[r][0], E, eNorm, idx, zn);
            if (sp < bv || (sp == bv && idx < bi)) { bv = sp; bi = idx; }
          }
        }
      }
    }
    fS[r][s] = bv;
    fiS[r][s] = bi;
  }
  __syncthreads();
  if (t < 32) {
    const int rcnt = ccnt[t], rhc = hcnt[t];
    int fidx;
    if (rcnt <= 1 && rhc == 0) {
      fidx = (int)(gK[t] & 0x3FFFu);   // sole window member == unique f32 argmin
    } else {
      float bv = fS[t][0];
      int bi = fiS[t][0];
#pragma unroll
      for (int s3 = 1; s3 < 8; ++s3) {
        float v = fS[t][s3];
        int id = fiS[t][s3];
        if (v < bv || (v == bv && id < bi)) { bv = v; bi = id; }
      }
      fidx = bi;
    }
    fI[t] = fidx;
    out_idx[n0 + t] = (float)fidx;
  }
  __syncthreads();

  // (D) gather + write + loss (z from LDS cache)
  const int idx = fI[r];
  const float4* erow4 = (const float4*)(E + (size_t)idx * E_DIM + s * 32);
  float* orow = out + ((size_t)b * E_DIM + s * 32) * HW + hw;
  float acc = 0.f;
#pragma unroll
  for (int c4 = 0; c4 < 8; ++c4) {
    float4 e4 = erow4[c4];
    float ev[4] = {e4.x, e4.y, e4.z, e4.w};
#pragma unroll
    for (int j2 = 0; j2 < 4; ++j2) {
      int c = c4 * 4 + j2;
      float zv = zc[r][s * 32 + c];
      orow[(size_t)c * HW] = ev[j2];
      float d = ev[j2] - zv;
      acc = fmaf(d, d, acc);
    }
  }
  for (int off = 32; off > 0; off >>= 1) acc += __shfl_down(acc, off, 64);
  if ((t & 63) == 0) wsum[t >> 6] = acc;
  __syncthreads();
  if (t == 0)
    atomicAdd(out_loss, ((wsum[0] + wsum[1]) + (wsum[2] + wsum[3])) * (1.25f / 2097152.f));
}

extern "C" void kernel_launch(void* const* d_in, const int* in_sizes, int n_in,
                              void* d_out, int out_size, void* d_ws, size_t ws_size,
                              hipStream_t stream) {
  const float* z = (const float*)d_in[0];
  const float* E = (const float*)d_in[1];
  float* out = (float*)d_out;
  float* out_loss = out + 2097152;  // after z_q (8*256*32*32)
  float* out_idx = out + 2097153;

  // workspace (~16 MB): Ah f16[8][8192][32], Bh f16[8][16384][32],
  //                     eNorm, zL1, zNorm, pK1|pK2 u32[64][8192]
  _Float16* Ah = (_Float16*)d_ws;
  _Float16* Bh = Ah + (size_t)N_ROWS * E_DIM;
  float* eNorm = (float*)(Bh + (size_t)N_E * E_DIM);
  float* zL1 = eNorm + N_E;
  float* zNorm = zL1 + N_ROWS;
  unsigned* pK1 = (unsigned*)(zNorm + N_ROWS);
  unsigned* pK2 = pK1 + (size_t)NPART * N_ROWS;

  k_prep<<<ZB_Z + EB_E, 256, 0, stream>>>(z, E, Ah, Bh, eNorm, zNorm, zL1, out_loss);
  k_scores_mfma<<<dim3(N_ROWS / 256, N_E / 256), 512, 0, stream>>>(
      Ah, Bh, eNorm, pK1, pK2);
  k_post<<<N_ROWS / 32, 256, 0, stream>>>(
      pK1, pK2, zL1, zNorm, z, E, eNorm, out, out_loss, out_idx);
}

// Round 7
// 330.767 us; speedup vs baseline: 1.6763x; 1.6763x over previous
//
#include <hip/hip_runtime.h>

#define E_DIM  256
#define N_E    16384
#define N_ROWS 8192
#define HW     1024
#define NPART  64           // n-tiles of 256 cols

typedef _Float16 f16x8 __attribute__((ext_vector_type(8)));
typedef float    f32x4 __attribute__((ext_vector_type(4)));

#define ESCALE   1048576.0f          // 2^20 (exact)
#define UNSCALE  1.9073486328125e-6f // 2^-19: acc*2^-19 == 2*dot (approx, single limb)

// async 16B global->LDS copy: HW writes lds_base + lane*16 (wave-uniform base)
__device__ __forceinline__ void gld_lds16(_Float16* lds, const _Float16* g) {
  __builtin_amdgcn_global_load_lds(
      (__attribute__((address_space(1))) void*)(g),
      (__attribute__((address_space(3))) void*)(lds), 16, 0, 0);
}

// reference-semantics f32 score: fl32(fl32(zn+en) - fl32(2*dot)).
// All dot intermediates are ~1e-4 scale (|e|<6.1e-5), so f32 summation error
// ~1e-9 << final-subtraction ulp 3e-5: same f32 bucket as numpy's einsum.
// 4 independent partial sums -> ILP-4, no serial chain (R18's f64 chain was
// the 455us straggler). Equal buckets resolve by lex idx (caller).
__device__ __forceinline__ float score_ref32(const float* zr,
                                             const float* __restrict__ E,
                                             const float* __restrict__ eNorm,
                                             int idx, float zn) {
  const float4* e4p = (const float4*)(E + (size_t)idx * E_DIM);
  float d0 = 0.f, d1 = 0.f, d2 = 0.f, d3 = 0.f;
#pragma unroll 8
  for (int q = 0; q < 64; ++q) {
    float4 e4 = e4p[q];
    d0 = fmaf(zr[q * 4 + 0], e4.x, d0);
    d1 = fmaf(zr[q * 4 + 1], e4.y, d1);
    d2 = fmaf(zr[q * 4 + 2], e4.z, d2);
    d3 = fmaf(zr[q * 4 + 3], e4.w, d3);
  }
  float dot = (d0 + d1) + (d2 + d3);
  float base = zn + eNorm[idx];   // f32 add, matches np broadcast add
  float td = 2.0f * dot;          // exact (power of 2)
  return base - td;               // f32 final rounding at the reference ulp
}

// ---------- fused prep: single-limb A/B + eNorm + numpy-exact zNorm + z L1 ----------
#define ZB_Z    256
#define EB_E    512
__global__ __launch_bounds__(256) void k_prep(const float* __restrict__ z,
                                              const float* __restrict__ E,
                                              _Float16* __restrict__ Ah,
                                              _Float16* __restrict__ Bh,
                                              float* __restrict__ eNorm,
                                              float* __restrict__ zNorm,
                                              float* __restrict__ zL1,
                                              float* __restrict__ out_loss) {
#pragma clang fp contract(off)
  const int bi = blockIdx.x, t = threadIdx.x;

  if (bi < ZB_Z) {
    // ---- z section: 32-row tile ----
    __shared__ float sLZ[256][32];   // 32 KB z tile [channel][row]
    __shared__ float sN2[16][32];    // square-chain partials [c16][row]
    __shared__ float sL1[16][32];    // abs-chain partials
    const int n0 = bi * 32;
    const int b = n0 >> 10, hw0 = n0 & 1023;

    {
      const int nl = t & 31, cs = t >> 5;
      const float* zb = z + (size_t)b * E_DIM * HW + hw0 + nl;
#pragma unroll 4
      for (int it = 0; it < 32; ++it) {
        int c = it * 8 + cs;
        sLZ[c][nl] = zb[(size_t)c * HW];
      }
    }
    __syncthreads();

    // phase L: high limb only. thread = (row nl, segment seg = kc)
    {
      const int nl = t & 31, seg = t >> 5;
      const int n = n0 + nl;
      const int perm = (n >> 1) & 3;
#pragma unroll
      for (int u = 0; u < 4; ++u) {
        const int c0 = seg * 32 + u * 8;
        f16x8 hh;
#pragma unroll
        for (int j = 0; j < 8; ++j) hh[j] = (_Float16)sLZ[c0 + j][nl];
        size_t dst = (size_t)seg * (N_ROWS * 32) + (size_t)n * 32 + (size_t)(u ^ perm) * 8;
        *(f16x8*)&Ah[dst] = hh;
      }
    }

    // phase N: numpy-exact square chains (zNorm) + abs chains (zL1 window scale)
#pragma unroll
    for (int it = 0; it < 2; ++it) {
      int task = it * 256 + t;
      int nl = task & 31, c16 = task >> 5;
      int h = c16 >> 3, j = c16 & 7;
      float r2 = 0.f, r1 = 0.f;
#pragma unroll
      for (int i = 0; i < 16; ++i) {
        float v = sLZ[h * 128 + i * 8 + j][nl];
        r2 = r2 + v * v;
        r1 = r1 + fabsf(v);
      }
      sN2[c16][nl] = r2;
      sL1[c16][nl] = r1;
    }
    __syncthreads();
    if (t < 32) {
      float q[16], p[16];
#pragma unroll
      for (int c16 = 0; c16 < 16; ++c16) { q[c16] = sN2[c16][t]; p[c16] = sL1[c16][t]; }
      float h0 = ((q[0] + q[1]) + (q[2] + q[3])) + ((q[4] + q[5]) + (q[6] + q[7]));
      float h1 = ((q[8] + q[9]) + (q[10] + q[11])) + ((q[12] + q[13]) + (q[14] + q[15]));
      zNorm[n0 + t] = h0 + h1;
      float g0 = ((p[0] + p[1]) + (p[2] + p[3])) + ((p[4] + p[5]) + (p[6] + p[7]));
      float g1 = ((p[8] + p[9]) + (p[10] + p[11])) + ((p[12] + p[13]) + (p[14] + p[15]));
      zL1[n0 + t] = g0 + g1;
    }
  } else {
    // ---- E section ----
    __shared__ float sNP[8][32];
    const int be = bi - ZB_Z;
    if (be == 0 && t == 0) out_loss[0] = 0.f;
    const int kc = t >> 5, rl = t & 31;
    const int k = be * 32 + rl;
    const int perm = (k >> 1) & 3;
    const float* src = E + (size_t)k * E_DIM + kc * 32;

    float4 v4[8];
#pragma unroll
    for (int u2 = 0; u2 < 8; ++u2) v4[u2] = ((const float4*)src)[u2];

    float nsum = 0.f;
    size_t base = (size_t)kc * (N_E * 32) + (size_t)k * 32;
#pragma unroll
    for (int u = 0; u < 4; ++u) {
      float v[8] = {v4[u * 2].x, v4[u * 2].y, v4[u * 2].z, v4[u * 2].w,
                    v4[u * 2 + 1].x, v4[u * 2 + 1].y, v4[u * 2 + 1].z, v4[u * 2 + 1].w};
      f16x8 hh;
#pragma unroll
      for (int j = 0; j < 8; ++j) {
        nsum = nsum + v[j] * v[j];
        hh[j] = (_Float16)(v[j] * ESCALE);
      }
      *(f16x8*)&Bh[base + (size_t)(u ^ perm) * 8] = hh;
    }
    sNP[kc][rl] = nsum;
    __syncthreads();
    if (t < 32) {
      float s = 0.f;
#pragma unroll
      for (int kc2 = 0; kc2 < 8; ++kc2) s += sNP[kc2][t];
      eNorm[be * 32 + t] = s;
    }
  }
}

// ---------- main: single-limb approx GEMM + branchless packed-key top-2.
// key = quantize18(s) << 14 | idx  (s in (-1/16,1/16) guaranteed by
// |2 z.e| <= 2||z|| ||e|| < 0.04); u32 min == lex (s, idx) min.
// Quantizer folded into one fmaf: UNSCALE*2^21 == 4.0 exactly. (verbatim R18)
__global__ __launch_bounds__(512, 2) void k_scores_mfma(
    const _Float16* __restrict__ Ah, const _Float16* __restrict__ Bh,
    const float* __restrict__ eNorm,
    unsigned* __restrict__ pK1, unsigned* __restrict__ pK2) {
#pragma clang fp contract(off)
  __shared__ alignas(16) _Float16 As[2][256][32];  // 32 KB (dbuf)
  __shared__ alignas(16) _Float16 Bs[2][256][32];  // 32 KB

  const int mt = blockIdx.x, nt = blockIdx.y;
  const int m0 = mt * 256, n0 = nt * 256;

  const int t = threadIdx.x;
  const int lane = t & 63, w = t >> 6;
  const int tx = lane & 15, quad = lane >> 4;
  const int wr = w & 3, wc = w >> 2;          // wave grid 4 (m) x 2 (n)
  const int wm = wr * 64, wn = wc * 128;      // per-wave output 64 x 128
  const int swz = (quad ^ ((tx >> 1) & 3)) * 8;  // physical f16 offset of logical block

  // staging role: waves 0-3 stage A rows [w*64,w*64+64), waves 4-7 stage B
  const _Float16* gstage;
  size_t plane;
  _Float16* ls0;
  if (w < 4) { gstage = Ah + (size_t)(m0 + w * 64) * 32;       plane = (size_t)N_ROWS * 32; ls0 = &As[0][w * 64][0]; }
  else       { gstage = Bh + (size_t)(n0 + (w - 4) * 64) * 32; plane = (size_t)N_E * 32;    ls0 = &Bs[0][(w - 4) * 64][0]; }
  gstage += lane * 8;

  f32x4 acc[4][8];
#pragma unroll
  for (int i = 0; i < 4; ++i)
#pragma unroll
    for (int j = 0; j < 8; ++j) acc[i][j] = (f32x4){0.f, 0.f, 0.f, 0.f};

  // prologue: stage kc=0 into buf 0 (4 x 1KB per wave)
#pragma unroll
  for (int c = 0; c < 4; ++c) gld_lds16(ls0 + c * 512, gstage + c * 512);
  __syncthreads();

  for (int kc = 0; kc < 8; ++kc) {
    const int buf = kc & 1;

    if (kc < 7) {
      _Float16* lpre = ls0 + (size_t)(buf ^ 1) * 8192;
      const _Float16* gpre = gstage + (size_t)(kc + 1) * plane;
#pragma unroll
      for (int c = 0; c < 4; ++c) gld_lds16(lpre + c * 512, gpre + c * 512);
      __builtin_amdgcn_sched_barrier(0);   // pin prefetch issue before compute
    }

    f16x8 ah[4], bh[8];
#pragma unroll
    for (int i = 0; i < 4; ++i)
      ah[i] = *(const f16x8*)&As[buf][wm + i * 16 + tx][swz];
#pragma unroll
    for (int j = 0; j < 8; ++j)
      bh[j] = *(const f16x8*)&Bs[buf][wn + j * 16 + tx][swz];

    __builtin_amdgcn_s_setprio(1);
#pragma unroll
    for (int j = 0; j < 8; ++j)
#pragma unroll
      for (int i = 0; i < 4; ++i)
        acc[i][j] = __builtin_amdgcn_mfma_f32_16x16x32_f16(ah[i], bh[j], acc[i][j], 0, 0, 0);
    __builtin_amdgcn_s_setprio(0);

    __syncthreads();   // kc boundary: drains prefetch (1 full kc of cover) + frag reads
  }

  // ---- epilogue: branchless packed-key top-2 per (row, tile) ----
  float* sF  = (float*)&As[0][0][0];
  float* eNq = sF;                          // [256] quantized-domain eNorm
  unsigned* sK1 = (unsigned*)(sF + 256);    // [2][256]
  unsigned* sK2 = sK1 + 512;                // [2][256]
  if (t < 256) eNq[t] = fmaf(eNorm[n0 + t], 2097152.f, 131072.f);
  __syncthreads();

#pragma unroll
  for (int i = 0; i < 4; ++i) {
#pragma unroll
    for (int r = 0; r < 4; ++r) {
      const int rloc = wm + i * 16 + quad * 4 + r;
      unsigned m1 = 0xFFFFFFFFu, m2 = 0xFFFFFFFFu;
#pragma unroll
      for (int jj = 0; jj < 8; ++jj) {
        const int col = wn + jj * 16 + tx;
        float tq = fmaf(acc[i][jj][r], -4.0f, eNq[col]);   // (s - SMIN)*2^21
        unsigned key = (((unsigned)tq) << 14) | (unsigned)(n0 + col);
        m2 = min(m2, max(m1, key));
        m1 = min(m1, key);
      }
#pragma unroll
      for (int off = 1; off < 16; off <<= 1) {
        unsigned om1 = (unsigned)__shfl_xor((int)m1, off, 64);
        unsigned om2 = (unsigned)__shfl_xor((int)m2, off, 64);
        m2 = min(min(m2, om2), max(m1, om1));
        m1 = min(m1, om1);
      }
      if (tx == 0) { sK1[wc * 256 + rloc] = m1; sK2[wc * 256 + rloc] = m2; }
    }
  }
  __syncthreads();
  if (t < 256) {
    unsigned a1 = sK1[t], a2 = sK2[t];
    unsigned b1 = sK1[256 + t], b2 = sK2[256 + t];
    const size_t o = (size_t)nt * N_ROWS + m0 + t;
    pK1[o] = min(a1, b1);
    pK2[o] = min(max(a1, b1), min(a2, b2));
  }
}

// ---------- fused post: key-domain window + f32 reference rescore ----------
__global__ __launch_bounds__(256) void k_post(
    const unsigned* __restrict__ pK1, const unsigned* __restrict__ pK2,
    const float* __restrict__ zL1, const float* __restrict__ zNorm,
    const float* __restrict__ z, const float* __restrict__ E,
    const float* __restrict__ eNorm,
    float* __restrict__ out, float* __restrict__ out_loss,
    float* __restrict__ out_idx) {
#pragma clang fp contract(off)
  __shared__ float zc[32][260];     // z rows cache (+pad)
  __shared__ unsigned sM[8][32];
  __shared__ unsigned gK[32];
  __shared__ int   fI[32];
  __shared__ int   cand[32][16];
  __shared__ int   ccnt[32];
  __shared__ int   heavy[32][4];
  __shared__ int   hcnt[32];
  __shared__ float fS[32][8];
  __shared__ int   fiS[32][8];
  __shared__ float wsum[4];

  const int t = threadIdx.x;
  const int r = t & 31, s = t >> 5;
  const int n0 = blockIdx.x * 32;
  const int n = n0 + r;
  const int b = n >> 10, hw = n & 1023;

  if (t < 32) { ccnt[t] = 0; hcnt[t] = 0; }

  // cache this row's z (reused by rescore AND final gather/loss)
  {
    const float* zrow = z + ((size_t)b * E_DIM + s * 32) * HW + hw;
#pragma unroll
    for (int k = 0; k < 32; ++k) zc[r][s * 32 + k] = zrow[(size_t)k * HW];
  }

  // (A) global approx min over 64 tiles (u32 key min == lex (s, idx) min)
  unsigned mk = 0xFFFFFFFFu;
#pragma unroll
  for (int i = 0; i < 8; ++i) {
    int ti = s * 8 + i;
    mk = min(mk, pK1[(size_t)ti * N_ROWS + n]);
  }
  sM[s][r] = mk;
  __syncthreads();
  if (t < 32) {
    unsigned bk = sM[0][t];
#pragma unroll
    for (int s3 = 1; s3 < 8; ++s3) bk = min(bk, sM[s3][t]);
    gK[t] = bk;
  }
  __syncthreads();

  // (B) window in key space: W = 2^-22*||z||_1 + 8e-5, +3 quant steps slack
  {
    const unsigned qW =
        (unsigned)(fmaf(zL1[n], 2.384185791015625e-7f, 8e-5f) * 2097152.f) + 3u;
    unsigned thrq = (gK[r] >> 14) + qW;
    if (thrq > 262143u) thrq = 262143u;
    const unsigned thrk = (thrq << 14) | 0x3FFFu;
#pragma unroll
    for (int i = 0; i < 8; ++i) {
      int ti = s * 8 + i;
      size_t o = (size_t)ti * N_ROWS + n;
      unsigned k1 = pK1[o], k2 = pK2[o];
      if (k1 <= thrk) { int p = atomicAdd(&ccnt[r], 1); if (p < 16) cand[r][p] = (int)(k1 & 0x3FFFu); }
      if (k2 <= thrk) { int p = atomicAdd(&hcnt[r], 1); if (p < 4)  heavy[r][p] = ti; }
    }
  }
  __syncthreads();

  // (C) f32 reference rescore of window members; lexicographic (s_p, idx) min
  {
    const int rcnt = ccnt[r], rhc = hcnt[r];
    const bool ovf = (rcnt > 16) || (rhc > 4);
    const bool ex = (rcnt > 1) || (rhc > 0);
    float bv = 3.4e38f;
    int bi = 0x7fffffff;
    if (ex) {
      const float zn = zNorm[n];
      if (ovf) {
        for (int k = s; k < N_E; k += 8) {
          float sp = score_ref32(&zc[r][0], E, eNorm, k, zn);
          if (sp < bv || (sp == bv && k < bi)) { bv = sp; bi = k; }
        }
      } else {
        for (int c = s; c < rcnt; c += 8) {
          int idx = cand[r][c];
          float sp = score_ref32(&zc[r][0], E, eNorm, idx, zn);
          if (sp < bv || (sp == bv && idx < bi)) { bv = sp; bi = idx; }
        }
        for (int h = 0; h < rhc; ++h) {
          int ti = heavy[r][h];
          for (int cc = s; cc < 256; cc += 8) {
            int idx = ti * 256 + cc;
            float sp = score_ref32(&zc[r][0], E, eNorm, idx, zn);
            if (sp < bv || (sp == bv && idx < bi)) { bv = sp; bi = idx; }
          }
        }
      }
    }
    fS[r][s] = bv;
    fiS[r][s] = bi;
  }
  __syncthreads();
  if (t < 32) {
    const int rcnt = ccnt[t], rhc = hcnt[t];
    int fidx;
    if (rcnt <= 1 && rhc == 0) {
      fidx = (int)(gK[t] & 0x3FFFu);   // sole window member == unique f32 argmin
    } else {
      float bv = fS[t][0];
      int bi = fiS[t][0];
#pragma unroll
      for (int s3 = 1; s3 < 8; ++s3) {
        float v = fS[t][s3];
        int id = fiS[t][s3];
        if (v < bv || (v == bv && id < bi)) { bv = v; bi = id; }
      }
      fidx = bi;
    }
    fI[t] = fidx;
    out_idx[n0 + t] = (float)fidx;
  }
  __syncthreads();

  // (D) gather + write + loss (z from LDS cache)
  const int idx = fI[r];
  const float4* erow4 = (const float4*)(E + (size_t)idx * E_DIM + s * 32);
  float* orow = out + ((size_t)b * E_DIM + s * 32) * HW + hw;
  float acc = 0.f;
#pragma unroll
  for (int c4 = 0; c4 < 8; ++c4) {
    float4 e4 = erow4[c4];
    float ev[4] = {e4.x, e4.y, e4.z, e4.w};
#pragma unroll
    for (int j2 = 0; j2 < 4; ++j2) {
      int c = c4 * 4 + j2;
      float zv = zc[r][s * 32 + c];
      orow[(size_t)c * HW] = ev[j2];
      float d = ev[j2] - zv;
      acc = fmaf(d, d, acc);
    }
  }
  for (int off = 32; off > 0; off >>= 1) acc += __shfl_down(acc, off, 64);
  if ((t & 63) == 0) wsum[t >> 6] = acc;
  __syncthreads();
  if (t == 0)
    atomicAdd(out_loss, ((wsum[0] + wsum[1]) + (wsum[2] + wsum[3])) * (1.25f / 2097152.f));
}

extern "C" void kernel_launch(void* const* d_in, const int* in_sizes, int n_in,
                              void* d_out, int out_size, void* d_ws, size_t ws_size,
                              hipStream_t stream) {
  const float* z = (const float*)d_in[0];
  const float* E = (const float*)d_in[1];
  float* out = (float*)d_out;
  float* out_loss = out + 2097152;  // after z_q (8*256*32*32)
  float* out_idx = out + 2097153;

  // workspace (~16 MB): Ah f16[8][8192][32], Bh f16[8][16384][32],
  //                     eNorm, zL1, zNorm, pK1|pK2 u32[64][8192]
  _Float16* Ah = (_Float16*)d_ws;
  _Float16* Bh = Ah + (size_t)N_ROWS * E_DIM;
  float* eNorm = (float*)(Bh + (size_t)N_E * E_DIM);
  float* zL1 = eNorm + N_E;
  float* zNorm = zL1 + N_ROWS;
  unsigned* pK1 = (unsigned*)(zNorm + N_ROWS);
  unsigned* pK2 = pK1 + (size_t)NPART * N_ROWS;

  k_prep<<<ZB_Z + EB_E, 256, 0, stream>>>(z, E, Ah, Bh, eNorm, zNorm, zL1, out_loss);
  k_scores_mfma<<<dim3(N_ROWS / 256, N_E / 256), 512, 0, stream>>>(
      Ah, Bh, eNorm, pK1, pK2);
  k_post<<<N_ROWS / 32, 256, 0, stream>>>(
      pK1, pK2, zL1, zNorm, z, E, eNorm, out, out_loss, out_idx);
}

// Round 8
// 216.286 us; speedup vs baseline: 2.5636x; 1.5293x over previous
//
#include <hip/hip_runtime.h>

#define E_DIM  256
#define N_E    16384
#define N_ROWS 8192
#define HW     1024
#define NPART  64           // n-tiles of 256 cols

typedef _Float16 f16x8 __attribute__((ext_vector_type(8)));
typedef float    f32x4 __attribute__((ext_vector_type(4)));

#define ESCALE   1048576.0f          // 2^20 (exact)
#define UNSCALE  1.9073486328125e-6f // 2^-19: acc*2^-19 == 2*dot (approx, single limb)

// async 16B global->LDS copy: HW writes lds_base + lane*16 (wave-uniform base)
__device__ __forceinline__ void gld_lds16(_Float16* lds, const _Float16* g) {
  __builtin_amdgcn_global_load_lds(
      (__attribute__((address_space(1))) void*)(g),
      (__attribute__((address_space(3))) void*)(lds), 16, 0, 0);
}

// reference-semantics f32 score: fl32(fl32(zn+en) - fl32(2*dot)).
// All dot intermediates are ~1e-4 scale (|e|<6.1e-5): f32 sum error ~1e-9 <<
// final-subtraction ulp 3e-5 -> same f32 bucket as numpy's einsum.
// unroll 16 -> 16 loads in flight (HBM-latency-bound path).
__device__ __forceinline__ float score_ref32(const float* zr,
                                             const float* __restrict__ E,
                                             const float* __restrict__ eNorm,
                                             int idx, float zn) {
  const float4* e4p = (const float4*)(E + (size_t)idx * E_DIM);
  float d0 = 0.f, d1 = 0.f, d2 = 0.f, d3 = 0.f;
#pragma unroll 16
  for (int q = 0; q < 64; ++q) {
    float4 e4 = e4p[q];
    d0 = fmaf(zr[q * 4 + 0], e4.x, d0);
    d1 = fmaf(zr[q * 4 + 1], e4.y, d1);
    d2 = fmaf(zr[q * 4 + 2], e4.z, d2);
    d3 = fmaf(zr[q * 4 + 3], e4.w, d3);
  }
  float dot = (d0 + d1) + (d2 + d3);
  float base = zn + eNorm[idx];   // f32 add, matches np broadcast add
  float td = 2.0f * dot;          // exact (power of 2)
  return base - td;               // f32 final rounding at the reference ulp
}

// ---------- fused prep: single-limb A/B + eNorm + numpy-exact zNorm + z L1 ----------
#define ZB_Z    256
#define EB_E    512
__global__ __launch_bounds__(256) void k_prep(const float* __restrict__ z,
                                              const float* __restrict__ E,
                                              _Float16* __restrict__ Ah,
                                              _Float16* __restrict__ Bh,
                                              float* __restrict__ eNorm,
                                              float* __restrict__ zNorm,
                                              float* __restrict__ zL1,
                                              float* __restrict__ out_loss) {
#pragma clang fp contract(off)
  const int bi = blockIdx.x, t = threadIdx.x;

  if (bi < ZB_Z) {
    // ---- z section: 32-row tile ----
    __shared__ float sLZ[256][32];   // 32 KB z tile [channel][row]
    __shared__ float sN2[16][32];    // square-chain partials [c16][row]
    __shared__ float sL1[16][32];    // abs-chain partials
    const int n0 = bi * 32;
    const int b = n0 >> 10, hw0 = n0 & 1023;

    {
      const int nl = t & 31, cs = t >> 5;
      const float* zb = z + (size_t)b * E_DIM * HW + hw0 + nl;
#pragma unroll 4
      for (int it = 0; it < 32; ++it) {
        int c = it * 8 + cs;
        sLZ[c][nl] = zb[(size_t)c * HW];
      }
    }
    __syncthreads();

    // phase L: high limb only. thread = (row nl, segment seg = kc)
    {
      const int nl = t & 31, seg = t >> 5;
      const int n = n0 + nl;
      const int perm = (n >> 1) & 3;
#pragma unroll
      for (int u = 0; u < 4; ++u) {
        const int c0 = seg * 32 + u * 8;
        f16x8 hh;
#pragma unroll
        for (int j = 0; j < 8; ++j) hh[j] = (_Float16)sLZ[c0 + j][nl];
        size_t dst = (size_t)seg * (N_ROWS * 32) + (size_t)n * 32 + (size_t)(u ^ perm) * 8;
        *(f16x8*)&Ah[dst] = hh;
      }
    }

    // phase N: numpy-exact square chains (zNorm) + abs chains (zL1 window scale)
#pragma unroll
    for (int it = 0; it < 2; ++it) {
      int task = it * 256 + t;
      int nl = task & 31, c16 = task >> 5;
      int h = c16 >> 3, j = c16 & 7;
      float r2 = 0.f, r1 = 0.f;
#pragma unroll
      for (int i = 0; i < 16; ++i) {
        float v = sLZ[h * 128 + i * 8 + j][nl];
        r2 = r2 + v * v;
        r1 = r1 + fabsf(v);
      }
      sN2[c16][nl] = r2;
      sL1[c16][nl] = r1;
    }
    __syncthreads();
    if (t < 32) {
      float q[16], p[16];
#pragma unroll
      for (int c16 = 0; c16 < 16; ++c16) { q[c16] = sN2[c16][t]; p[c16] = sL1[c16][t]; }
      float h0 = ((q[0] + q[1]) + (q[2] + q[3])) + ((q[4] + q[5]) + (q[6] + q[7]));
      float h1 = ((q[8] + q[9]) + (q[10] + q[11])) + ((q[12] + q[13]) + (q[14] + q[15]));
      zNorm[n0 + t] = h0 + h1;
      float g0 = ((p[0] + p[1]) + (p[2] + p[3])) + ((p[4] + p[5]) + (p[6] + p[7]));
      float g1 = ((p[8] + p[9]) + (p[10] + p[11])) + ((p[12] + p[13]) + (p[14] + p[15]));
      zL1[n0 + t] = g0 + g1;
    }
  } else {
    // ---- E section ----
    __shared__ float sNP[8][32];
    const int be = bi - ZB_Z;
    if (be == 0 && t == 0) out_loss[0] = 0.f;
    const int kc = t >> 5, rl = t & 31;
    const int k = be * 32 + rl;
    const int perm = (k >> 1) & 3;
    const float* src = E + (size_t)k * E_DIM + kc * 32;

    float4 v4[8];
#pragma unroll
    for (int u2 = 0; u2 < 8; ++u2) v4[u2] = ((const float4*)src)[u2];

    float nsum = 0.f;
    size_t base = (size_t)kc * (N_E * 32) + (size_t)k * 32;
#pragma unroll
    for (int u = 0; u < 4; ++u) {
      float v[8] = {v4[u * 2].x, v4[u * 2].y, v4[u * 2].z, v4[u * 2].w,
                    v4[u * 2 + 1].x, v4[u * 2 + 1].y, v4[u * 2 + 1].z, v4[u * 2 + 1].w};
      f16x8 hh;
#pragma unroll
      for (int j = 0; j < 8; ++j) {
        nsum = nsum + v[j] * v[j];
        hh[j] = (_Float16)(v[j] * ESCALE);
      }
      *(f16x8*)&Bh[base + (size_t)(u ^ perm) * 8] = hh;
    }
    sNP[kc][rl] = nsum;
    __syncthreads();
    if (t < 32) {
      float s = 0.f;
#pragma unroll
      for (int kc2 = 0; kc2 < 8; ++kc2) s += sNP[kc2][t];
      eNorm[be * 32 + t] = s;
    }
  }
}

// ---------- main: single-limb approx GEMM + branchless packed-key TOP-3.
// key = quantize18(s) << 14 | idx; u32 min == lex (s, idx) min.
// Top-3 keys per (row, tile): k1/k2 carry candidate indices, k3 is the
// "are there >=3 in window" guard (kills R19's frequent heavy-tile scans).
__global__ __launch_bounds__(512, 2) void k_scores_mfma(
    const _Float16* __restrict__ Ah, const _Float16* __restrict__ Bh,
    const float* __restrict__ eNorm,
    unsigned* __restrict__ pK1, unsigned* __restrict__ pK2,
    unsigned* __restrict__ pK3) {
#pragma clang fp contract(off)
  __shared__ alignas(16) _Float16 As[2][256][32];  // 32 KB (dbuf)
  __shared__ alignas(16) _Float16 Bs[2][256][32];  // 32 KB

  const int mt = blockIdx.x, nt = blockIdx.y;
  const int m0 = mt * 256, n0 = nt * 256;

  const int t = threadIdx.x;
  const int lane = t & 63, w = t >> 6;
  const int tx = lane & 15, quad = lane >> 4;
  const int wr = w & 3, wc = w >> 2;          // wave grid 4 (m) x 2 (n)
  const int wm = wr * 64, wn = wc * 128;      // per-wave output 64 x 128
  const int swz = (quad ^ ((tx >> 1) & 3)) * 8;  // physical f16 offset of logical block

  // staging role: waves 0-3 stage A rows [w*64,w*64+64), waves 4-7 stage B
  const _Float16* gstage;
  size_t plane;
  _Float16* ls0;
  if (w < 4) { gstage = Ah + (size_t)(m0 + w * 64) * 32;       plane = (size_t)N_ROWS * 32; ls0 = &As[0][w * 64][0]; }
  else       { gstage = Bh + (size_t)(n0 + (w - 4) * 64) * 32; plane = (size_t)N_E * 32;    ls0 = &Bs[0][(w - 4) * 64][0]; }
  gstage += lane * 8;

  f32x4 acc[4][8];
#pragma unroll
  for (int i = 0; i < 4; ++i)
#pragma unroll
    for (int j = 0; j < 8; ++j) acc[i][j] = (f32x4){0.f, 0.f, 0.f, 0.f};

  // prologue: stage kc=0 into buf 0 (4 x 1KB per wave)
#pragma unroll
  for (int c = 0; c < 4; ++c) gld_lds16(ls0 + c * 512, gstage + c * 512);
  __syncthreads();

  for (int kc = 0; kc < 8; ++kc) {
    const int buf = kc & 1;

    if (kc < 7) {
      _Float16* lpre = ls0 + (size_t)(buf ^ 1) * 8192;
      const _Float16* gpre = gstage + (size_t)(kc + 1) * plane;
#pragma unroll
      for (int c = 0; c < 4; ++c) gld_lds16(lpre + c * 512, gpre + c * 512);
      __builtin_amdgcn_sched_barrier(0);   // pin prefetch issue before compute
    }

    f16x8 ah[4], bh[8];
#pragma unroll
    for (int i = 0; i < 4; ++i)
      ah[i] = *(const f16x8*)&As[buf][wm + i * 16 + tx][swz];
#pragma unroll
    for (int j = 0; j < 8; ++j)
      bh[j] = *(const f16x8*)&Bs[buf][wn + j * 16 + tx][swz];

    __builtin_amdgcn_s_setprio(1);
#pragma unroll
    for (int j = 0; j < 8; ++j)
#pragma unroll
      for (int i = 0; i < 4; ++i)
        acc[i][j] = __builtin_amdgcn_mfma_f32_16x16x32_f16(ah[i], bh[j], acc[i][j], 0, 0, 0);
    __builtin_amdgcn_s_setprio(0);

    __syncthreads();   // kc boundary: drains prefetch (1 full kc of cover) + frag reads
  }

  // ---- epilogue: branchless packed-key top-3 per (row, tile) ----
  float* sF  = (float*)&As[0][0][0];
  float* eNq = sF;                          // [256] quantized-domain eNorm
  unsigned* sK1 = (unsigned*)(sF + 256);    // [2][256]
  unsigned* sK2 = sK1 + 512;                // [2][256]
  unsigned* sK3 = sK2 + 512;                // [2][256]
  if (t < 256) eNq[t] = fmaf(eNorm[n0 + t], 2097152.f, 131072.f);
  __syncthreads();

#pragma unroll
  for (int i = 0; i < 4; ++i) {
#pragma unroll
    for (int r = 0; r < 4; ++r) {
      const int rloc = wm + i * 16 + quad * 4 + r;
      unsigned m1 = 0xFFFFFFFFu, m2 = 0xFFFFFFFFu, m3 = 0xFFFFFFFFu;
#pragma unroll
      for (int jj = 0; jj < 8; ++jj) {
        const int col = wn + jj * 16 + tx;
        float tq = fmaf(acc[i][jj][r], -4.0f, eNq[col]);   // (s - SMIN)*2^21
        unsigned key = (((unsigned)tq) << 14) | (unsigned)(n0 + col);
        unsigned t2 = max(m1, key);       // insert into sorted triple
        m1 = min(m1, key);
        unsigned t3 = max(m2, t2);
        m2 = min(m2, t2);
        m3 = min(m3, t3);
      }
#pragma unroll
      for (int off = 1; off < 16; off <<= 1) {
        unsigned b1 = (unsigned)__shfl_xor((int)m1, off, 64);
        unsigned b2 = (unsigned)__shfl_xor((int)m2, off, 64);
        unsigned b3 = (unsigned)__shfl_xor((int)m3, off, 64);
        unsigned c1 = min(m1, b1);
        unsigned c2 = min(max(m1, b1), min(m2, b2));
        unsigned c3 = min(min(m3, b3), min(max(m2, b1), max(m1, b2)));
        m1 = c1; m2 = c2; m3 = c3;
      }
      if (tx == 0) {
        sK1[wc * 256 + rloc] = m1;
        sK2[wc * 256 + rloc] = m2;
        sK3[wc * 256 + rloc] = m3;
      }
    }
  }
  __syncthreads();
  if (t < 256) {
    unsigned a1 = sK1[t], a2 = sK2[t], a3 = sK3[t];
    unsigned b1 = sK1[256 + t], b2 = sK2[256 + t], b3 = sK3[256 + t];
    const size_t o = (size_t)nt * N_ROWS + m0 + t;
    pK1[o] = min(a1, b1);
    pK2[o] = min(max(a1, b1), min(a2, b2));
    pK3[o] = min(min(a3, b3), min(max(a2, b1), max(a1, b2)));
  }
}

// ---------- fused post: key-domain window + f32 reference rescore ----------
__global__ __launch_bounds__(256) void k_post(
    const unsigned* __restrict__ pK1, const unsigned* __restrict__ pK2,
    const unsigned* __restrict__ pK3,
    const float* __restrict__ zL1, const float* __restrict__ zNorm,
    const float* __restrict__ z, const float* __restrict__ E,
    const float* __restrict__ eNorm,
    float* __restrict__ out, float* __restrict__ out_loss,
    float* __restrict__ out_idx) {
#pragma clang fp contract(off)
  __shared__ float zc[32][260];     // z rows cache (+pad)
  __shared__ unsigned sM[8][32];
  __shared__ unsigned gK[32];
  __shared__ int   fI[32];
  __shared__ int   cand[32][16];
  __shared__ int   ccnt[32];
  __shared__ int   heavy[32][4];
  __shared__ int   hcnt[32];
  __shared__ float fS[32][8];
  __shared__ int   fiS[32][8];
  __shared__ float wsum[4];

  const int t = threadIdx.x;
  const int r = t & 31, s = t >> 5;
  const int n0 = blockIdx.x * 32;
  const int n = n0 + r;
  const int b = n >> 10, hw = n & 1023;

  if (t < 32) { ccnt[t] = 0; hcnt[t] = 0; }

  // cache this row's z (reused by rescore AND final gather/loss)
  {
    const float* zrow = z + ((size_t)b * E_DIM + s * 32) * HW + hw;
#pragma unroll
    for (int k = 0; k < 32; ++k) zc[r][s * 32 + k] = zrow[(size_t)k * HW];
  }

  // (A) global approx min over 64 tiles (u32 key min == lex (s, idx) min)
  unsigned mk = 0xFFFFFFFFu;
#pragma unroll
  for (int i = 0; i < 8; ++i) {
    int ti = s * 8 + i;
    mk = min(mk, pK1[(size_t)ti * N_ROWS + n]);
  }
  sM[s][r] = mk;
  __syncthreads();
  if (t < 32) {
    unsigned bk = sM[0][t];
#pragma unroll
    for (int s3 = 1; s3 < 8; ++s3) bk = min(bk, sM[s3][t]);
    gK[t] = bk;
  }
  __syncthreads();

  // (B) window in key space: W = 2^-22*||z||_1 + 8e-5, +3 quant steps slack.
  // k1,k2 in window -> direct candidates (idx packed); k3 in window -> heavy.
  {
    const unsigned qW =
        (unsigned)(fmaf(zL1[n], 2.384185791015625e-7f, 8e-5f) * 2097152.f) + 3u;
    unsigned thrq = (gK[r] >> 14) + qW;
    if (thrq > 262143u) thrq = 262143u;
    const unsigned thrk = (thrq << 14) | 0x3FFFu;
#pragma unroll
    for (int i = 0; i < 8; ++i) {
      int ti = s * 8 + i;
      size_t o = (size_t)ti * N_ROWS + n;
      unsigned k1 = pK1[o], k2 = pK2[o], k3 = pK3[o];
      if (k1 <= thrk) { int p = atomicAdd(&ccnt[r], 1); if (p < 16) cand[r][p] = (int)(k1 & 0x3FFFu); }
      if (k2 <= thrk) { int p = atomicAdd(&ccnt[r], 1); if (p < 16) cand[r][p] = (int)(k2 & 0x3FFFu); }
      if (k3 <= thrk) { int p = atomicAdd(&hcnt[r], 1); if (p < 4)  heavy[r][p] = ti; }
    }
  }
  __syncthreads();

  // (C) f32 reference rescore of window members; lexicographic (s_p, idx) min
  {
    const int rcnt = ccnt[r], rhc = hcnt[r];
    const bool ovf = (rcnt > 16) || (rhc > 4);
    const bool ex = (rcnt > 1) || (rhc > 0);
    float bv = 3.4e38f;
    int bi = 0x7fffffff;
    if (ex) {
      const float zn = zNorm[n];
      if (ovf) {
        for (int k = s; k < N_E; k += 8) {
          float sp = score_ref32(&zc[r][0], E, eNorm, k, zn);
          if (sp < bv || (sp == bv && k < bi)) { bv = sp; bi = k; }
        }
      } else {
        for (int c = s; c < rcnt; c += 8) {
          int idx = cand[r][c];
          float sp = score_ref32(&zc[r][0], E, eNorm, idx, zn);
          if (sp < bv || (sp == bv && idx < bi)) { bv = sp; bi = idx; }
        }
        for (int h = 0; h < rhc; ++h) {
          int ti = heavy[r][h];
          for (int cc = s; cc < 256; cc += 8) {
            int idx = ti * 256 + cc;
            float sp = score_ref32(&zc[r][0], E, eNorm, idx, zn);
            if (sp < bv || (sp == bv && idx < bi)) { bv = sp; bi = idx; }
          }
        }
      }
    }
    fS[r][s] = bv;
    fiS[r][s] = bi;
  }
  __syncthreads();
  if (t < 32) {
    const int rcnt = ccnt[t], rhc = hcnt[t];
    int fidx;
    if (rcnt <= 1 && rhc == 0) {
      fidx = (int)(gK[t] & 0x3FFFu);   // sole window member == unique f32 argmin
    } else {
      float bv = fS[t][0];
      int bi = fiS[t][0];
#pragma unroll
      for (int s3 = 1; s3 < 8; ++s3) {
        float v = fS[t][s3];
        int id = fiS[t][s3];
        if (v < bv || (v == bv && id < bi)) { bv = v; bi = id; }
      }
      fidx = bi;
    }
    fI[t] = fidx;
    out_idx[n0 + t] = (float)fidx;
  }
  __syncthreads();

  // (D) gather + write + loss (z from LDS cache)
  const int idx = fI[r];
  const float4* erow4 = (const float4*)(E + (size_t)idx * E_DIM + s * 32);
  float* orow = out + ((size_t)b * E_DIM + s * 32) * HW + hw;
  float acc = 0.f;
#pragma unroll
  for (int c4 = 0; c4 < 8; ++c4) {
    float4 e4 = erow4[c4];
    float ev[4] = {e4.x, e4.y, e4.z, e4.w};
#pragma unroll
    for (int j2 = 0; j2 < 4; ++j2) {
      int c = c4 * 4 + j2;
      float zv = zc[r][s * 32 + c];
      orow[(size_t)c * HW] = ev[j2];
      float d = ev[j2] - zv;
      acc = fmaf(d, d, acc);
    }
  }
  for (int off = 32; off > 0; off >>= 1) acc += __shfl_down(acc, off, 64);
  if ((t & 63) == 0) wsum[t >> 6] = acc;
  __syncthreads();
  if (t == 0)
    atomicAdd(out_loss, ((wsum[0] + wsum[1]) + (wsum[2] + wsum[3])) * (1.25f / 2097152.f));
}

extern "C" void kernel_launch(void* const* d_in, const int* in_sizes, int n_in,
                              void* d_out, int out_size, void* d_ws, size_t ws_size,
                              hipStream_t stream) {
  const float* z = (const float*)d_in[0];
  const float* E = (const float*)d_in[1];
  float* out = (float*)d_out;
  float* out_loss = out + 2097152;  // after z_q (8*256*32*32)
  float* out_idx = out + 2097153;

  // workspace (~18 MB): Ah f16[8][8192][32], Bh f16[8][16384][32],
  //                     eNorm, zL1, zNorm, pK1|pK2|pK3 u32[64][8192]
  _Float16* Ah = (_Float16*)d_ws;
  _Float16* Bh = Ah + (size_t)N_ROWS * E_DIM;
  float* eNorm = (float*)(Bh + (size_t)N_E * E_DIM);
  float* zL1 = eNorm + N_E;
  float* zNorm = zL1 + N_ROWS;
  unsigned* pK1 = (unsigned*)(zNorm + N_ROWS);
  unsigned* pK2 = pK1 + (size_t)NPART * N_ROWS;
  unsigned* pK3 = pK2 + (size_t)NPART * N_ROWS;

  k_prep<<<ZB_Z + EB_E, 256, 0, stream>>>(z, E, Ah, Bh, eNorm, zNorm, zL1, out_loss);
  k_scores_mfma<<<dim3(N_ROWS / 256, N_E / 256), 512, 0, stream>>>(
      Ah, Bh, eNorm, pK1, pK2, pK3);
  k_post<<<N_ROWS / 32, 256, 0, stream>>>(
      pK1, pK2, pK3, zL1, zNorm, z, E, eNorm, out, out_loss, out_idx);
}